// Round 1
// baseline (309.362 us; speedup 1.0000x reference)
//
#include <hip/hip_runtime.h>

// Problem constants (match reference)
#define BB 8
#define NN 65536
#define DD 192
#define EPSV 1e-5f
#define NPTS (BB * NN)       // 524288
#define NBLK 1024            // main-kernel blocks (512 thr, 1 point/thread)

// d_out layout: dss [B*N] | nss [B*N*3] | loss [1]
// d_ws: partial[NBLK] floats (block partial sums of min(dss,0))
//
// Journal (R1-R5): dur_us carries ~210 us fixed harness restore/poison tax
// (top-5 dispatches are all 135-us 864-MiB fillBuffer poisons at 84% HBM).
// Kernel-attributable ~98 us vs ~40 us random-gather HBM floor (~170 MB of
// cold 64-128B lines; the 900-MB poison flushes L3 between iterations, so the
// grid is never L3-resident at kernel start).
// R6 theory: old config (1024x256x2pt) = 4 blk/CU = 16 waves/CU — HALF of HW
// wave capacity; random-gather misses are latency-bound, not BW-bound.
// Change: 1024 x 512thr x 1pt => 32 waves/CU (needs VGPR<=64 via
// __launch_bounds__(512,8)); NT stores/loads for streaming data keep L2
// capacity for grid lines (batch-affinity swizzle kept: batch == blockIdx&7).

__global__ __launch_bounds__(512, 8) void tri_sdf_kernel(
    const float* __restrict__ pss,     // [B,3,N]
    const float* __restrict__ grid,    // [B,D,D,D]
    const float* __restrict__ first,   // [B,3]
    const float* __restrict__ coef,    // [B,3]
    const float* __restrict__ maxl,    // [B,3]
    float* __restrict__ dss,           // [B*N]
    float* __restrict__ nss,           // [B*N,3]
    float* __restrict__ partial)       // [NBLK]
{
    // XCD batch affinity: batch == blockIdx & 7 (round-robin block->XCD).
    // Each block covers 512 consecutive points of one batch (65536/512 = 128
    // blocks per batch, exact).
    const int vb = ((int)blockIdx.x & 7) * 128 + ((int)blockIdx.x >> 3);
    const int t0 = vb * 512 + (int)threadIdx.x;
    const int b  = t0 >> 16;           // uniform within block
    const int n0 = t0 & (NN - 1);

    // --- coalesced, non-temporal point loads (read-once stream) ---
    const float* pb = pss + (size_t)b * 3 * NN + n0;
    const float px = __builtin_nontemporal_load(pb);
    const float py = __builtin_nontemporal_load(pb + NN);
    const float pz = __builtin_nontemporal_load(pb + 2 * NN);

    // batch-uniform params -> scalar loads
    const float f0x = first[3*b+0], f0y = first[3*b+1], f0z = first[3*b+2];
    const float cfx = coef[3*b+0],  cfy = coef[3*b+1],  cfz = coef[3*b+2];
    const float mlx = maxl[3*b+0],  mly = maxl[3*b+1],  mlz = maxl[3*b+2];

    const float Fx = fmaxf(fminf((px - f0x) * cfx, mlx), 0.0f);
    const float Fy = fmaxf(fminf((py - f0y) * cfy, mly), 0.0f);
    const float Fz = fmaxf(fminf((pz - f0z) * cfz, mlz), 0.0f);

    const int bx = (int)floorf(Fx), by = (int)floorf(Fy), bz = (int)floorf(Fz);
    const float fx = Fx - (float)bx, fy = Fy - (float)by, fz = Fz - (float)bz;

    // --- issue all 8 corner loads before any use ---
    const float* g = grid + (size_t)b * DD * DD * DD
                   + ((size_t)((bx * DD + by) * DD + bz));
    const float a000 = g[0];
    const float a001 = g[1];
    const float a010 = g[DD];
    const float a011 = g[DD + 1];
    const float a100 = g[DD * DD];
    const float a101 = g[DD * DD + 1];
    const float a110 = g[DD * DD + DD];
    const float a111 = g[DD * DD + DD + 1];

    const float wx0 = 1.0f - fx, wx1 = fx;
    const float wy0 = 1.0f - fy, wy1 = fy;
    const float wz0 = 1.0f - fz, wz1 = fz;

    const float d00 = wz0 * a000 + wz1 * a001;
    const float d01 = wz0 * a010 + wz1 * a011;
    const float d10 = wz0 * a100 + wz1 * a101;
    const float d11 = wz0 * a110 + wz1 * a111;
    const float dv  = wx0 * (wy0 * d00 + wy1 * d01)
                    + wx1 * (wy0 * d10 + wy1 * d11);

    const float nz = wx0 * (wy0 * (a001 - a000) + wy1 * (a011 - a010))
                   + wx1 * (wy0 * (a101 - a100) + wy1 * (a111 - a110));
    const float ny = wx0 * (wz0 * (a010 - a000) + wz1 * (a011 - a001))
                   + wx1 * (wz0 * (a110 - a100) + wz1 * (a111 - a101));
    const float nx = wy0 * (wz0 * (a100 - a000) + wz1 * (a101 - a001))
                   + wy1 * (wz0 * (a110 - a010) + wz1 * (a111 - a011));
    const float inv = 1.0f / fmaxf(sqrtf(nx*nx + ny*ny + nz*nz), EPSV);

    // --- non-temporal stores (write-once stream; keep L2 for grid lines) ---
    __builtin_nontemporal_store(dv, dss + t0);
    float* np = nss + (size_t)t0 * 3;
    __builtin_nontemporal_store(nx * inv, np + 0);
    __builtin_nontemporal_store(ny * inv, np + 1);
    __builtin_nontemporal_store(nz * inv, np + 2);

    // --- block partial of sum(min(dss,0)): shuffle -> LDS -> plain store ---
    float lp = fminf(dv, 0.0f);
    #pragma unroll
    for (int off = 32; off > 0; off >>= 1)
        lp += __shfl_down(lp, off, 64);
    __shared__ float wsum[8];
    const int wid = threadIdx.x >> 6;
    if ((threadIdx.x & 63) == 0) wsum[wid] = lp;
    __syncthreads();
    if (threadIdx.x == 0) {
        float s = wsum[0] + wsum[1] + wsum[2] + wsum[3]
                + wsum[4] + wsum[5] + wsum[6] + wsum[7];
        partial[blockIdx.x] = s;
    }
}

// 1024 partials -> loss = -sum  (single block, no atomics anywhere)
__global__ __launch_bounds__(256) void loss_reduce_kernel(
    const float* __restrict__ partial, float* __restrict__ loss)
{
    const int tid = threadIdx.x;
    float s = partial[tid] + partial[tid + 256]
            + partial[tid + 512] + partial[tid + 768];
    #pragma unroll
    for (int off = 32; off > 0; off >>= 1)
        s += __shfl_down(s, off, 64);
    __shared__ float wsum[4];
    const int wid = tid >> 6;
    if ((tid & 63) == 0) wsum[wid] = s;
    __syncthreads();
    if (tid == 0)
        loss[0] = -(wsum[0] + wsum[1] + wsum[2] + wsum[3]);
}

extern "C" void kernel_launch(void* const* d_in, const int* in_sizes, int n_in,
                              void* d_out, int out_size, void* d_ws, size_t ws_size,
                              hipStream_t stream) {
    const float* pss   = (const float*)d_in[0];
    const float* grid  = (const float*)d_in[1];
    const float* first = (const float*)d_in[2];
    const float* coef  = (const float*)d_in[3];
    const float* maxl  = (const float*)d_in[4];

    float* out  = (float*)d_out;
    float* dss  = out;                          // B*N
    float* nss  = out + (size_t)BB * NN;        // B*N*3
    float* loss = out + (size_t)4 * BB * NN;    // 1

    float* partial = (float*)d_ws;              // NBLK floats

    tri_sdf_kernel<<<NBLK, 512, 0, stream>>>(pss, grid, first, coef, maxl,
                                             dss, nss, partial);
    loss_reduce_kernel<<<1, 256, 0, stream>>>(partial, loss);
}